// Round 7
// baseline (1019.000 us; speedup 1.0000x reference)
//
#include <hip/hip_runtime.h>

#define NHEADS 8
#define NB 512
#define NN 1000
#define DD 128
#define HH 128
#define SDIM 384              // D*CAT
#define NSPLIT 10             // blocks per batch
#define NSLOT (NSPLIT * 2)    // one partial slot per wave
#define RPW 50                // rows per wave (25 pairs)
#define NPAIR (RPW / 2)       // 25

// DPP helper: x += lane-permuted x. Pure VALU, no DS pipe.
template <int CTRL>
__device__ __forceinline__ float dpp_add(float x) {
    int y = __builtin_amdgcn_update_dpp(0, __float_as_int(x), CTRL, 0xf, 0xf, true);
    return x + __int_as_float(y);
}
#define DPP_QUAD_XOR1 0xB1   // quad_perm(1,0,3,2)
#define DPP_QUAD_XOR2 0x4E   // quad_perm(2,3,0,1)
#define DPP_HALF_MIRR 0x141  // mirror within 8
#define DPP_ROW_MIRR  0x140  // mirror within 16

// ---------------- kernel 0: per-batch qw precompute (coalesced) -------------
__global__ __launch_bounds__(256) void qw_kernel(
    const float* __restrict__ state_t,   // [B][384]
    const float* __restrict__ Wq,        // [128][384]
    const float* __restrict__ Wk,        // [128][128]
    float* __restrict__ qw)              // [B][8][128]
{
    const int b = blockIdx.x;
    const int t = threadIdx.x;
    const int lane = t & 63;
    const int w = t >> 6;

    __shared__ float s_q[HH];

    float st[6];
    #pragma unroll
    for (int j = 0; j < 6; ++j) st[j] = state_t[(size_t)b * SDIM + j * 64 + lane];

    for (int it = 0; it < 16; ++it) {
        const int r0 = w * 32 + it * 2;
        const float* w0 = Wq + (size_t)r0 * SDIM;
        const float* w1 = w0 + SDIM;
        float p0 = 0.f, p1 = 0.f;
        #pragma unroll
        for (int j = 0; j < 6; ++j) {
            p0 = fmaf(w0[j * 64 + lane], st[j], p0);
            p1 = fmaf(w1[j * 64 + lane], st[j], p1);
        }
        #pragma unroll
        for (int off = 32; off >= 1; off >>= 1) {
            p0 += __shfl_xor(p0, off, 64);
            p1 += __shfl_xor(p1, off, 64);
        }
        if (lane == 0) { s_q[r0] = p0; s_q[r0 + 1] = p1; }
    }
    __syncthreads();

    {
        const int d  = t & 127;
        const int h0 = (t >> 7) * 4;
        const float sc = 0.0625f * 1.4426950408889634f;  // (1/hd) * log2(e)
        for (int hh = 0; hh < 4; ++hh) {
            const int h = h0 + hh;
            float a = 0.f;
            #pragma unroll
            for (int j = 0; j < 16; ++j)
                a = fmaf(s_q[h * 16 + j], Wk[(size_t)(h * 16 + j) * DD + d], a);
            qw[(size_t)b * NHEADS * DD + h * DD + d] = a * sc;
        }
    }
}

// Load a row-pair into named buffers. (paste followed by space+'=' is legal)
#define LOADP(P, pairidx)                                                     \
    {                                                                         \
        const float* _np = cp + (size_t)(2 * (pairidx)) * DD;                 \
        P##00 = *reinterpret_cast<const float4*>(_np);                        \
        P##01 = *reinterpret_cast<const float4*>(_np + 4);                    \
        P##10 = *reinterpret_cast<const float4*>(_np + DD);                   \
        P##11 = *reinterpret_cast<const float4*>(_np + DD + 4);               \
        P##m0 = mp[2 * (pairidx)];                                            \
        P##m1 = mp[2 * (pairidx) + 1];                                        \
    }

// Process pair P, then refill P with pair (itn + 3), clamped to last pair.
// Copy pasted names into SSA locals first (avoids `x00.x` pp-token pasting;
// copies are register renames, zero cost).
#define PROC(P, itn)                                                          \
    {                                                                         \
        const float4 C00 = P##00, C01 = P##01, C10 = P##10, C11 = P##11;      \
        const int M0 = P##m0, M1 = P##m1;                                     \
        float sa0 = C00.x * qa0.x, sb0 = C00.x * qb0.x;                       \
        float sa1 = C10.x * qa0.x, sb1 = C10.x * qb0.x;                       \
        sa0 = fmaf(C00.y, qa0.y, sa0); sb0 = fmaf(C00.y, qb0.y, sb0);         \
        sa1 = fmaf(C10.y, qa0.y, sa1); sb1 = fmaf(C10.y, qb0.y, sb1);         \
        sa0 = fmaf(C00.z, qa0.z, sa0); sb0 = fmaf(C00.z, qb0.z, sb0);         \
        sa1 = fmaf(C10.z, qa0.z, sa1); sb1 = fmaf(C10.z, qb0.z, sb1);         \
        sa0 = fmaf(C00.w, qa0.w, sa0); sb0 = fmaf(C00.w, qb0.w, sb0);         \
        sa1 = fmaf(C10.w, qa0.w, sa1); sb1 = fmaf(C10.w, qb0.w, sb1);         \
        sa0 = fmaf(C01.x, qa1.x, sa0); sb0 = fmaf(C01.x, qb1.x, sb0);         \
        sa1 = fmaf(C11.x, qa1.x, sa1); sb1 = fmaf(C11.x, qb1.x, sb1);         \
        sa0 = fmaf(C01.y, qa1.y, sa0); sb0 = fmaf(C01.y, qb1.y, sb0);         \
        sa1 = fmaf(C11.y, qa1.y, sa1); sb1 = fmaf(C11.y, qb1.y, sb1);         \
        sa0 = fmaf(C01.z, qa1.z, sa0); sb0 = fmaf(C01.z, qb1.z, sb0);         \
        sa1 = fmaf(C11.z, qa1.z, sa1); sb1 = fmaf(C11.z, qb1.z, sb1);         \
        sa0 = fmaf(C01.w, qa1.w, sa0); sb0 = fmaf(C01.w, qb1.w, sb0);         \
        sa1 = fmaf(C11.w, qa1.w, sa1); sb1 = fmaf(C11.w, qb1.w, sb1);         \
        sa0 = dpp_add<DPP_QUAD_XOR1>(sa0); sb0 = dpp_add<DPP_QUAD_XOR1>(sb0); \
        sa1 = dpp_add<DPP_QUAD_XOR1>(sa1); sb1 = dpp_add<DPP_QUAD_XOR1>(sb1); \
        sa0 = dpp_add<DPP_QUAD_XOR2>(sa0); sb0 = dpp_add<DPP_QUAD_XOR2>(sb0); \
        sa1 = dpp_add<DPP_QUAD_XOR2>(sa1); sb1 = dpp_add<DPP_QUAD_XOR2>(sb1); \
        sa0 = dpp_add<DPP_HALF_MIRR>(sa0); sb0 = dpp_add<DPP_HALF_MIRR>(sb0); \
        sa1 = dpp_add<DPP_HALF_MIRR>(sa1); sb1 = dpp_add<DPP_HALF_MIRR>(sb1); \
        sa0 = dpp_add<DPP_ROW_MIRR>(sa0);  sb0 = dpp_add<DPP_ROW_MIRR>(sb0);  \
        sa1 = dpp_add<DPP_ROW_MIRR>(sa1);  sb1 = dpp_add<DPP_ROW_MIRR>(sb1);  \
        const float pa0 = M0 ? 0.f : exp2f(sa0);                              \
        const float pb0 = M0 ? 0.f : exp2f(sb0);                              \
        const float pa1 = M1 ? 0.f : exp2f(sa1);                              \
        const float pb1 = M1 ? 0.f : exp2f(sb1);                              \
        den0 += pa0 + pa1;                                                    \
        den1 += pb0 + pb1;                                                    \
        A0.x = fmaf(pa0, C00.x, fmaf(pa1, C10.x, A0.x));                      \
        A0.y = fmaf(pa0, C00.y, fmaf(pa1, C10.y, A0.y));                      \
        A0.z = fmaf(pa0, C00.z, fmaf(pa1, C10.z, A0.z));                      \
        A0.w = fmaf(pa0, C00.w, fmaf(pa1, C10.w, A0.w));                      \
        A1.x = fmaf(pa0, C01.x, fmaf(pa1, C11.x, A1.x));                      \
        A1.y = fmaf(pa0, C01.y, fmaf(pa1, C11.y, A1.y));                      \
        A1.z = fmaf(pa0, C01.z, fmaf(pa1, C11.z, A1.z));                      \
        A1.w = fmaf(pa0, C01.w, fmaf(pa1, C11.w, A1.w));                      \
        B0.x = fmaf(pb0, C00.x, fmaf(pb1, C10.x, B0.x));                      \
        B0.y = fmaf(pb0, C00.y, fmaf(pb1, C10.y, B0.y));                      \
        B0.z = fmaf(pb0, C00.z, fmaf(pb1, C10.z, B0.z));                      \
        B0.w = fmaf(pb0, C00.w, fmaf(pb1, C10.w, B0.w));                      \
        B1.x = fmaf(pb0, C01.x, fmaf(pb1, C11.x, B1.x));                      \
        B1.y = fmaf(pb0, C01.y, fmaf(pb1, C11.y, B1.y));                      \
        B1.z = fmaf(pb0, C01.z, fmaf(pb1, C11.z, B1.z));                      \
        B1.w = fmaf(pb0, C01.w, fmaf(pb1, C11.w, B1.w));                      \
        int _pr = (itn) + 3;                                                  \
        if (_pr > NPAIR - 1) _pr = NPAIR - 1;                                 \
        LOADP(P, _pr)                                                         \
    }

// ---------------- kernel 1: fused partial + last-block combine --------------
// Block = (split s, batch b), 128 threads = 2 waves; wave = 4 groups of 16
// lanes; group g = head pair (2g,2g+1); lane j owns floats [j*8, j*8+8).
// Row pairs with 3-buffer register rotation (load-use distance = 2 bodies).
__global__ __launch_bounds__(128, 4) void attn_fused_kernel(
    const float* __restrict__ context,   // [B][N][128]
    const int*   __restrict__ mask,      // [B][N]
    const float* __restrict__ qw,        // [B][8][128] (pre-scaled)
    const float* __restrict__ Wv,        // [128][128]
    const float* __restrict__ Wfc,       // [128][128]
    float* __restrict__ part_acc,        // [B][NSLOT][8][128]
    float* __restrict__ part_den,        // [B][NSLOT][8]
    int*   __restrict__ cnt,             // [B], zeroed before launch
    float* __restrict__ out)             // [B][128]
{
    const int s = blockIdx.x;
    const int b = blockIdx.y;
    const int w = threadIdx.x >> 6;
    const int lane = threadIdx.x & 63;
    const int g = lane >> 4;     // head pair
    const int j = lane & 15;     // d-slice

    // qw slices for heads 2g, 2g+1 (16 regs)
    const float* qwb = qw + (size_t)b * NHEADS * DD + j * 8;
    const float4 qa0 = *reinterpret_cast<const float4*>(qwb + (2 * g) * DD);
    const float4 qa1 = *reinterpret_cast<const float4*>(qwb + (2 * g) * DD + 4);
    const float4 qb0 = *reinterpret_cast<const float4*>(qwb + (2 * g + 1) * DD);
    const float4 qb1 = *reinterpret_cast<const float4*>(qwb + (2 * g + 1) * DD + 4);

    float4 A0 = make_float4(0.f, 0.f, 0.f, 0.f), A1 = A0;  // acc head 2g
    float4 B0 = A0, B1 = A0;                                // acc head 2g+1
    float den0 = 0.f, den1 = 0.f;

    const int row0 = s * (2 * RPW) + w * RPW;
    const float* cp = context + ((size_t)b * NN + row0) * DD + j * 8;
    const int*   mp = mask + (size_t)b * NN + row0;

    // 3 pipeline pair-buffers, all named locals (keep out of scratch!)
    float4 x00, x01, x10, x11; int xm0, xm1;
    float4 y00, y01, y10, y11; int ym0, ym1;
    float4 z00, z01, z10, z11; int zm0, zm1;
    LOADP(x, 0)
    LOADP(y, 1)
    LOADP(z, 2)

    // 25 pairs = 8 triple-rounds (24) + 1 final
    for (int it = 0; it < 8; ++it) {
        PROC(x, 3 * it)
        PROC(y, 3 * it + 1)
        PROC(z, 3 * it + 2)
    }
    PROC(x, NPAIR - 1)

    // ---- write this wave's partial slot (no LDS, no barrier) ----
    const int slot = s * 2 + w;
    float* pa = part_acc + (((size_t)b * NSLOT + slot) * NHEADS) * DD + j * 8;
    *reinterpret_cast<float4*>(pa + (2 * g) * DD)         = A0;
    *reinterpret_cast<float4*>(pa + (2 * g) * DD + 4)     = A1;
    *reinterpret_cast<float4*>(pa + (2 * g + 1) * DD)     = B0;
    *reinterpret_cast<float4*>(pa + (2 * g + 1) * DD + 4) = B1;
    if (j == 0) {
        float* pd = part_den + ((size_t)b * NSLOT + slot) * NHEADS;
        pd[2 * g]     = den0;
        pd[2 * g + 1] = den1;
    }

    // ---- last block per batch does the combine ----
    __shared__ int s_last;
    __threadfence();                     // release partials (device scope)
    __syncthreads();
    if (threadIdx.x == 0)
        s_last = (atomicAdd(&cnt[b], 1) == NSPLIT - 1) ? 1 : 0;
    __syncthreads();
    if (!s_last) return;
    __threadfence();                     // acquire other blocks' partials

    __shared__ float s_dn[NHEADS];
    __shared__ float s_ca[NHEADS][132];
    __shared__ float s_o2[HH];
    const int t = threadIdx.x;           // 128 threads

    if (t < NHEADS) {
        float dn = 0.f;
        #pragma unroll
        for (int sp = 0; sp < NSLOT; ++sp)
            dn += part_den[((size_t)b * NSLOT + sp) * NHEADS + t];
        s_dn[t] = dn;
    }
    __syncthreads();

    {
        const int d = t;
        #pragma unroll
        for (int h = 0; h < NHEADS; ++h) {
            float a = 0.f;
            #pragma unroll
            for (int sp = 0; sp < NSLOT; ++sp)
                a += part_acc[(((size_t)b * NSLOT + sp) * NHEADS + h) * DD + d];
            s_ca[h][d] = a / s_dn[h];
        }
    }
    __syncthreads();

    {
        const int h = t >> 4;
        const float* wvr = Wv + (size_t)t * DD;
        float a = 0.f;
        #pragma unroll 4
        for (int d = 0; d < DD; ++d) a = fmaf(s_ca[h][d], wvr[d], a);
        s_o2[t] = a;
    }
    __syncthreads();

    {
        const float* wfc = Wfc + (size_t)t * DD;
        float a = 0.f;
        #pragma unroll 4
        for (int k = 0; k < DD; ++k) a = fmaf(s_o2[k], wfc[k], a);
        out[(size_t)b * HH + t] = a;
    }
}

extern "C" void kernel_launch(void* const* d_in, const int* in_sizes, int n_in,
                              void* d_out, int out_size, void* d_ws, size_t ws_size,
                              hipStream_t stream) {
    const float* state_t = (const float*)d_in[0];
    const float* context = (const float*)d_in[1];
    const int*   mask    = (const int*)d_in[2];
    const float* Wq      = (const float*)d_in[3];
    const float* Wk      = (const float*)d_in[4];
    const float* Wv      = (const float*)d_in[5];
    const float* Wfc     = (const float*)d_in[6];
    float* out = (float*)d_out;

    float* qw       = (float*)d_ws;                                  // 2 MB
    float* part_acc = qw + (size_t)NB * NHEADS * DD;                 // 42 MB
    float* part_den = part_acc + (size_t)NB * NSLOT * NHEADS * DD;   // 0.3 MB
    int*   cnt      = (int*)(part_den + (size_t)NB * NSLOT * NHEADS);

    hipMemsetAsync(cnt, 0, NB * sizeof(int), stream);
    qw_kernel<<<dim3(NB), dim3(256), 0, stream>>>(state_t, Wq, Wk, qw);
    attn_fused_kernel<<<dim3(NSPLIT, NB), dim3(128), 0, stream>>>(
        context, mask, qw, Wv, Wfc, part_acc, part_den, cnt, out);
}

// Round 8
// 678.530 us; speedup vs baseline: 1.5018x; 1.5018x over previous
//
#include <hip/hip_runtime.h>

#define NHEADS 8
#define NB 512
#define NN 1000
#define DD 128
#define HH 128
#define SDIM 384              // D*CAT
#define NSPLIT 10             // blocks per batch
#define NSLOT (NSPLIT * 2)    // one partial slot per wave
#define RPW 50                // rows per wave

// DPP helper: x += lane-permuted x. Pure VALU, no DS pipe.
template <int CTRL>
__device__ __forceinline__ float dpp_add(float x) {
    int y = __builtin_amdgcn_update_dpp(0, __float_as_int(x), CTRL, 0xf, 0xf, true);
    return x + __int_as_float(y);
}
#define DPP_QUAD_XOR1 0xB1   // quad_perm(1,0,3,2)
#define DPP_QUAD_XOR2 0x4E   // quad_perm(2,3,0,1)
#define DPP_HALF_MIRR 0x141  // mirror within 8
#define DPP_ROW_MIRR  0x140  // mirror within 16

// ---------------- kernel 0: per-batch qw precompute (coalesced) -------------
__global__ __launch_bounds__(256) void qw_kernel(
    const float* __restrict__ state_t,   // [B][384]
    const float* __restrict__ Wq,        // [128][384]
    const float* __restrict__ Wk,        // [128][128]
    float* __restrict__ qw)              // [B][8][128]
{
    const int b = blockIdx.x;
    const int t = threadIdx.x;
    const int lane = t & 63;
    const int w = t >> 6;

    __shared__ float s_q[HH];

    float st[6];
    #pragma unroll
    for (int j = 0; j < 6; ++j) st[j] = state_t[(size_t)b * SDIM + j * 64 + lane];

    for (int it = 0; it < 16; ++it) {
        const int r0 = w * 32 + it * 2;
        const float* w0 = Wq + (size_t)r0 * SDIM;
        const float* w1 = w0 + SDIM;
        float p0 = 0.f, p1 = 0.f;
        #pragma unroll
        for (int j = 0; j < 6; ++j) {
            p0 = fmaf(w0[j * 64 + lane], st[j], p0);
            p1 = fmaf(w1[j * 64 + lane], st[j], p1);
        }
        #pragma unroll
        for (int off = 32; off >= 1; off >>= 1) {
            p0 += __shfl_xor(p0, off, 64);
            p1 += __shfl_xor(p1, off, 64);
        }
        if (lane == 0) { s_q[r0] = p0; s_q[r0 + 1] = p1; }
    }
    __syncthreads();

    {
        const int d  = t & 127;
        const int h0 = (t >> 7) * 4;
        const float sc = 0.0625f * 1.4426950408889634f;  // (1/hd) * log2(e)
        for (int hh = 0; hh < 4; ++hh) {
            const int h = h0 + hh;
            float a = 0.f;
            #pragma unroll
            for (int j = 0; j < 16; ++j)
                a = fmaf(s_q[h * 16 + j], Wk[(size_t)(h * 16 + j) * DD + d], a);
            qw[(size_t)b * NHEADS * DD + h * DD + d] = a * sc;
        }
    }
}

// Load one row into a named buffer (a = first float4, b = second, m = mask).
#define LOADR(P, rowidx)                                                      \
    {                                                                         \
        const float* _np = cp + (size_t)(rowidx) * DD;                        \
        P##a = *reinterpret_cast<const float4*>(_np);                         \
        P##b = *reinterpret_cast<const float4*>(_np + 4);                     \
        P##m = mp[(rowidx)];                                                  \
    }

// Process one row from buffer P (SSA copies avoid pasted member access).
#define BODY(P)                                                               \
    {                                                                         \
        const float4 C0 = P##a, C1 = P##b;                                    \
        const int M = P##m;                                                   \
        float sa = C0.x * qa0.x, sb = C0.x * qb0.x;                           \
        sa = fmaf(C0.y, qa0.y, sa); sb = fmaf(C0.y, qb0.y, sb);               \
        sa = fmaf(C0.z, qa0.z, sa); sb = fmaf(C0.z, qb0.z, sb);               \
        sa = fmaf(C0.w, qa0.w, sa); sb = fmaf(C0.w, qb0.w, sb);               \
        sa = fmaf(C1.x, qa1.x, sa); sb = fmaf(C1.x, qb1.x, sb);               \
        sa = fmaf(C1.y, qa1.y, sa); sb = fmaf(C1.y, qb1.y, sb);               \
        sa = fmaf(C1.z, qa1.z, sa); sb = fmaf(C1.z, qb1.z, sb);               \
        sa = fmaf(C1.w, qa1.w, sa); sb = fmaf(C1.w, qb1.w, sb);               \
        sa = dpp_add<DPP_QUAD_XOR1>(sa); sb = dpp_add<DPP_QUAD_XOR1>(sb);     \
        sa = dpp_add<DPP_QUAD_XOR2>(sa); sb = dpp_add<DPP_QUAD_XOR2>(sb);     \
        sa = dpp_add<DPP_HALF_MIRR>(sa); sb = dpp_add<DPP_HALF_MIRR>(sb);     \
        sa = dpp_add<DPP_ROW_MIRR>(sa);  sb = dpp_add<DPP_ROW_MIRR>(sb);      \
        const float pa = M ? 0.f : exp2f(sa);                                 \
        const float pb = M ? 0.f : exp2f(sb);                                 \
        den0 += pa; den1 += pb;                                               \
        A0.x = fmaf(pa, C0.x, A0.x); B0.x = fmaf(pb, C0.x, B0.x);             \
        A0.y = fmaf(pa, C0.y, A0.y); B0.y = fmaf(pb, C0.y, B0.y);             \
        A0.z = fmaf(pa, C0.z, A0.z); B0.z = fmaf(pb, C0.z, B0.z);             \
        A0.w = fmaf(pa, C0.w, A0.w); B0.w = fmaf(pb, C0.w, B0.w);             \
        A1.x = fmaf(pa, C1.x, A1.x); B1.x = fmaf(pb, C1.x, B1.x);             \
        A1.y = fmaf(pa, C1.y, A1.y); B1.y = fmaf(pb, C1.y, B1.y);             \
        A1.z = fmaf(pa, C1.z, A1.z); B1.z = fmaf(pb, C1.z, B1.z);             \
        A1.w = fmaf(pa, C1.w, A1.w); B1.w = fmaf(pb, C1.w, B1.w);             \
    }

// ---------------- kernel 1: fused partial + last-block combine --------------
// Block = (split s, batch b), 128 threads = 2 waves; wave = 4 groups of 16
// lanes; group g = head pair (2g,2g+1); lane j owns floats [j*8, j*8+8).
// 1 row per body, 3 rotating single-row buffers (depth-3 prefetch distance),
// straight-line rotation: 15x3 main loop + fully peeled 5-body tail. No
// clamped/conditional prefetch addressing (R5/R7 spill lesson).
__global__ __launch_bounds__(128, 4) void attn_fused_kernel(
    const float* __restrict__ context,   // [B][N][128]
    const int*   __restrict__ mask,      // [B][N]
    const float* __restrict__ qw,        // [B][8][128] (pre-scaled)
    const float* __restrict__ Wv,        // [128][128]
    const float* __restrict__ Wfc,       // [128][128]
    float* __restrict__ part_acc,        // [B][NSLOT][8][128]
    float* __restrict__ part_den,        // [B][NSLOT][8]
    int*   __restrict__ cnt,             // [B], zeroed before launch
    float* __restrict__ out)             // [B][128]
{
    const int s = blockIdx.x;
    const int b = blockIdx.y;
    const int w = threadIdx.x >> 6;
    const int lane = threadIdx.x & 63;
    const int g = lane >> 4;     // head pair
    const int j = lane & 15;     // d-slice

    // qw slices for heads 2g, 2g+1 (16 regs)
    const float* qwb = qw + (size_t)b * NHEADS * DD + j * 8;
    const float4 qa0 = *reinterpret_cast<const float4*>(qwb + (2 * g) * DD);
    const float4 qa1 = *reinterpret_cast<const float4*>(qwb + (2 * g) * DD + 4);
    const float4 qb0 = *reinterpret_cast<const float4*>(qwb + (2 * g + 1) * DD);
    const float4 qb1 = *reinterpret_cast<const float4*>(qwb + (2 * g + 1) * DD + 4);

    float4 A0 = make_float4(0.f, 0.f, 0.f, 0.f), A1 = A0;  // acc head 2g
    float4 B0 = A0, B1 = A0;                                // acc head 2g+1
    float den0 = 0.f, den1 = 0.f;

    const int row0 = s * (2 * RPW) + w * RPW;
    const float* cp = context + ((size_t)b * NN + row0) * DD + j * 8;
    const int*   mp = mask + (size_t)b * NN + row0;

    // 3 rotating single-row buffers (named locals; ~27 floats)
    float4 p0a, p0b; int p0m;
    float4 p1a, p1b; int p1m;
    float4 p2a, p2b; int p2m;
    LOADR(p0, 0)
    LOADR(p1, 1)
    LOADR(p2, 2)

    // rows 0..44: 15 iterations x 3 bodies, each prefetches row k+3 (max 47)
    for (int it = 0; it < 15; ++it) {
        const int k = 3 * it;
        BODY(p0) LOADR(p0, k + 3)
        BODY(p1) LOADR(p1, k + 4)
        BODY(p2) LOADR(p2, k + 5)
    }
    // rows 45..49: peeled tail
    BODY(p0) LOADR(p0, 48)
    BODY(p1) LOADR(p1, 49)
    BODY(p2)           // row 47
    BODY(p0)           // row 48
    BODY(p1)           // row 49

    // ---- write this wave's partial slot (no LDS, no barrier) ----
    const int slot = s * 2 + w;
    float* pa_ = part_acc + (((size_t)b * NSLOT + slot) * NHEADS) * DD + j * 8;
    *reinterpret_cast<float4*>(pa_ + (2 * g) * DD)         = A0;
    *reinterpret_cast<float4*>(pa_ + (2 * g) * DD + 4)     = A1;
    *reinterpret_cast<float4*>(pa_ + (2 * g + 1) * DD)     = B0;
    *reinterpret_cast<float4*>(pa_ + (2 * g + 1) * DD + 4) = B1;
    if (j == 0) {
        float* pd = part_den + ((size_t)b * NSLOT + slot) * NHEADS;
        pd[2 * g]     = den0;
        pd[2 * g + 1] = den1;
    }

    // ---- last block per batch does the combine ----
    __shared__ int s_last;
    __threadfence();                     // release partials (device scope)
    __syncthreads();
    if (threadIdx.x == 0)
        s_last = (atomicAdd(&cnt[b], 1) == NSPLIT - 1) ? 1 : 0;
    __syncthreads();
    if (!s_last) return;
    __threadfence();                     // acquire other blocks' partials

    __shared__ float s_dn[NHEADS];
    __shared__ float s_ca[NHEADS][132];
    __shared__ float s_o2[HH];
    const int t = threadIdx.x;           // 128 threads

    if (t < NHEADS) {
        float dn = 0.f;
        #pragma unroll
        for (int sp = 0; sp < NSLOT; ++sp)
            dn += part_den[((size_t)b * NSLOT + sp) * NHEADS + t];
        s_dn[t] = dn;
    }
    __syncthreads();

    {
        const int d = t;
        #pragma unroll
        for (int h = 0; h < NHEADS; ++h) {
            float a = 0.f;
            #pragma unroll
            for (int sp = 0; sp < NSLOT; ++sp)
                a += part_acc[(((size_t)b * NSLOT + sp) * NHEADS + h) * DD + d];
            s_ca[h][d] = a / s_dn[h];
        }
    }
    __syncthreads();

    {
        const int h = t >> 4;
        const float* wvr = Wv + (size_t)t * DD;
        float a = 0.f;
        #pragma unroll 4
        for (int d = 0; d < DD; ++d) a = fmaf(s_ca[h][d], wvr[d], a);
        s_o2[t] = a;
    }
    __syncthreads();

    {
        const float* wfc = Wfc + (size_t)t * DD;
        float a = 0.f;
        #pragma unroll 4
        for (int k2 = 0; k2 < DD; ++k2) a = fmaf(s_o2[k2], wfc[k2], a);
        out[(size_t)b * HH + t] = a;
    }
}

extern "C" void kernel_launch(void* const* d_in, const int* in_sizes, int n_in,
                              void* d_out, int out_size, void* d_ws, size_t ws_size,
                              hipStream_t stream) {
    const float* state_t = (const float*)d_in[0];
    const float* context = (const float*)d_in[1];
    const int*   mask    = (const int*)d_in[2];
    const float* Wq      = (const float*)d_in[3];
    const float* Wk      = (const float*)d_in[4];
    const float* Wv      = (const float*)d_in[5];
    const float* Wfc     = (const float*)d_in[6];
    float* out = (float*)d_out;

    float* qw       = (float*)d_ws;                                  // 2 MB
    float* part_acc = qw + (size_t)NB * NHEADS * DD;                 // 21 MB
    float* part_den = part_acc + (size_t)NB * NSLOT * NHEADS * DD;   // 0.3 MB
    int*   cnt      = (int*)(part_den + (size_t)NB * NSLOT * NHEADS);

    hipMemsetAsync(cnt, 0, NB * sizeof(int), stream);
    qw_kernel<<<dim3(NB), dim3(256), 0, stream>>>(state_t, Wq, Wk, qw);
    attn_fused_kernel<<<dim3(NSPLIT, NB), dim3(128), 0, stream>>>(
        context, mask, qw, Wv, Wfc, part_acc, part_den, cnt, out);
}

// Round 9
// 131.503 us; speedup vs baseline: 7.7488x; 5.1598x over previous
//
#include <hip/hip_runtime.h>

#define NHEADS 8
#define NB 512
#define NN 1000
#define DD 128
#define HH 128
#define SDIM 384              // D*CAT
#define NSPLIT 10             // blocks per batch
#define NSLOT (NSPLIT * 2)    // one partial slot per wave
#define RPW 50                // rows per wave

// DPP helper: x += lane-permuted x. Pure VALU, no DS pipe.
template <int CTRL>
__device__ __forceinline__ float dpp_add(float x) {
    int y = __builtin_amdgcn_update_dpp(0, __float_as_int(x), CTRL, 0xf, 0xf, true);
    return x + __int_as_float(y);
}
#define DPP_QUAD_XOR1 0xB1   // quad_perm(1,0,3,2)
#define DPP_QUAD_XOR2 0x4E   // quad_perm(2,3,0,1)
#define DPP_HALF_MIRR 0x141  // mirror within 8
#define DPP_ROW_MIRR  0x140  // mirror within 16

// ---------------- kernel 0: per-batch qw precompute (coalesced) -------------
__global__ __launch_bounds__(256) void qw_kernel(
    const float* __restrict__ state_t,   // [B][384]
    const float* __restrict__ Wq,        // [128][384]
    const float* __restrict__ Wk,        // [128][128]
    float* __restrict__ qw)              // [B][8][128]
{
    const int b = blockIdx.x;
    const int t = threadIdx.x;
    const int lane = t & 63;
    const int w = t >> 6;

    __shared__ float s_q[HH];

    float st[6];
    #pragma unroll
    for (int j = 0; j < 6; ++j) st[j] = state_t[(size_t)b * SDIM + j * 64 + lane];

    for (int it = 0; it < 16; ++it) {
        const int r0 = w * 32 + it * 2;
        const float* w0 = Wq + (size_t)r0 * SDIM;
        const float* w1 = w0 + SDIM;
        float p0 = 0.f, p1 = 0.f;
        #pragma unroll
        for (int j = 0; j < 6; ++j) {
            p0 = fmaf(w0[j * 64 + lane], st[j], p0);
            p1 = fmaf(w1[j * 64 + lane], st[j], p1);
        }
        #pragma unroll
        for (int off = 32; off >= 1; off >>= 1) {
            p0 += __shfl_xor(p0, off, 64);
            p1 += __shfl_xor(p1, off, 64);
        }
        if (lane == 0) { s_q[r0] = p0; s_q[r0 + 1] = p1; }
    }
    __syncthreads();

    {
        const int d  = t & 127;
        const int h0 = (t >> 7) * 4;
        const float sc = 0.0625f * 1.4426950408889634f;  // (1/hd) * log2(e)
        for (int hh = 0; hh < 4; ++hh) {
            const int h = h0 + hh;
            float a = 0.f;
            #pragma unroll
            for (int j = 0; j < 16; ++j)
                a = fmaf(s_q[h * 16 + j], Wk[(size_t)(h * 16 + j) * DD + d], a);
            qw[(size_t)b * NHEADS * DD + h * DD + d] = a * sc;
        }
    }
}

// Load one row into a named buffer (a = first float4, b = second, m = mask).
#define LOADR(P, rowidx)                                                      \
    {                                                                         \
        const float* _np = cp + (size_t)(rowidx) * DD;                        \
        P##a = *reinterpret_cast<const float4*>(_np);                         \
        P##b = *reinterpret_cast<const float4*>(_np + 4);                     \
        P##m = mp[(rowidx)];                                                  \
    }

// Process one row from buffer P (SSA copies avoid pasted member access).
#define BODY(P)                                                               \
    {                                                                         \
        const float4 C0 = P##a, C1 = P##b;                                    \
        const int M = P##m;                                                   \
        float sa = C0.x * qa0.x, sb = C0.x * qb0.x;                           \
        sa = fmaf(C0.y, qa0.y, sa); sb = fmaf(C0.y, qb0.y, sb);               \
        sa = fmaf(C0.z, qa0.z, sa); sb = fmaf(C0.z, qb0.z, sb);               \
        sa = fmaf(C0.w, qa0.w, sa); sb = fmaf(C0.w, qb0.w, sb);               \
        sa = fmaf(C1.x, qa1.x, sa); sb = fmaf(C1.x, qb1.x, sb);               \
        sa = fmaf(C1.y, qa1.y, sa); sb = fmaf(C1.y, qb1.y, sb);               \
        sa = fmaf(C1.z, qa1.z, sa); sb = fmaf(C1.z, qb1.z, sb);               \
        sa = fmaf(C1.w, qa1.w, sa); sb = fmaf(C1.w, qb1.w, sb);               \
        sa = dpp_add<DPP_QUAD_XOR1>(sa); sb = dpp_add<DPP_QUAD_XOR1>(sb);     \
        sa = dpp_add<DPP_QUAD_XOR2>(sa); sb = dpp_add<DPP_QUAD_XOR2>(sb);     \
        sa = dpp_add<DPP_HALF_MIRR>(sa); sb = dpp_add<DPP_HALF_MIRR>(sb);     \
        sa = dpp_add<DPP_ROW_MIRR>(sa);  sb = dpp_add<DPP_ROW_MIRR>(sb);      \
        const float pa = M ? 0.f : exp2f(sa);                                 \
        const float pb = M ? 0.f : exp2f(sb);                                 \
        den0 += pa; den1 += pb;                                               \
        A0.x = fmaf(pa, C0.x, A0.x); B0.x = fmaf(pb, C0.x, B0.x);             \
        A0.y = fmaf(pa, C0.y, A0.y); B0.y = fmaf(pb, C0.y, B0.y);             \
        A0.z = fmaf(pa, C0.z, A0.z); B0.z = fmaf(pb, C0.z, B0.z);             \
        A0.w = fmaf(pa, C0.w, A0.w); B0.w = fmaf(pb, C0.w, B0.w);             \
        A1.x = fmaf(pa, C1.x, A1.x); B1.x = fmaf(pb, C1.x, B1.x);             \
        A1.y = fmaf(pa, C1.y, A1.y); B1.y = fmaf(pb, C1.y, B1.y);             \
        A1.z = fmaf(pa, C1.z, A1.z); B1.z = fmaf(pb, C1.z, B1.z);             \
        A1.w = fmaf(pa, C1.w, A1.w); B1.w = fmaf(pb, C1.w, B1.w);             \
    }

// ---------------- kernel 1: partial score+softmax-accumulate ----------------
// Block = (split s, batch b), 128 threads = 2 waves; wave = 4 groups of 16
// lanes; group g = head pair (2g,2g+1); lane j owns floats [j*8, j*8+8).
// 1 row per body, 3 rotating single-row buffers (depth-3 prefetch distance),
// straight-line rotation. NO fence, NO atomics — device-scope release fences
// cost ~0.7 ms chip-wide on 8-XCD (R8 lesson); combine is a separate kernel.
__global__ __launch_bounds__(128, 4) void attn_partial_kernel(
    const float* __restrict__ context,   // [B][N][128]
    const int*   __restrict__ mask,      // [B][N]
    const float* __restrict__ qw,        // [B][8][128] (pre-scaled)
    float* __restrict__ part_acc,        // [B][NSLOT][8][128]
    float* __restrict__ part_den)        // [B][NSLOT][8]
{
    const int s = blockIdx.x;
    const int b = blockIdx.y;
    const int w = threadIdx.x >> 6;
    const int lane = threadIdx.x & 63;
    const int g = lane >> 4;     // head pair
    const int j = lane & 15;     // d-slice

    // qw slices for heads 2g, 2g+1 (16 regs)
    const float* qwb = qw + (size_t)b * NHEADS * DD + j * 8;
    const float4 qa0 = *reinterpret_cast<const float4*>(qwb + (2 * g) * DD);
    const float4 qa1 = *reinterpret_cast<const float4*>(qwb + (2 * g) * DD + 4);
    const float4 qb0 = *reinterpret_cast<const float4*>(qwb + (2 * g + 1) * DD);
    const float4 qb1 = *reinterpret_cast<const float4*>(qwb + (2 * g + 1) * DD + 4);

    float4 A0 = make_float4(0.f, 0.f, 0.f, 0.f), A1 = A0;  // acc head 2g
    float4 B0 = A0, B1 = A0;                                // acc head 2g+1
    float den0 = 0.f, den1 = 0.f;

    const int row0 = s * (2 * RPW) + w * RPW;
    const float* cp = context + ((size_t)b * NN + row0) * DD + j * 8;
    const int*   mp = mask + (size_t)b * NN + row0;

    // 3 rotating single-row buffers (named locals; ~27 floats)
    float4 p0a, p0b; int p0m;
    float4 p1a, p1b; int p1m;
    float4 p2a, p2b; int p2m;
    LOADR(p0, 0)
    LOADR(p1, 1)
    LOADR(p2, 2)

    // rows 0..44: 15 iterations x 3 bodies, each prefetches row k+3 (max 47)
    for (int it = 0; it < 15; ++it) {
        const int k = 3 * it;
        BODY(p0) LOADR(p0, k + 3)
        BODY(p1) LOADR(p1, k + 4)
        BODY(p2) LOADR(p2, k + 5)
    }
    // rows 45..49: peeled tail
    BODY(p0) LOADR(p0, 48)
    BODY(p1) LOADR(p1, 49)
    BODY(p2)           // row 47
    BODY(p0)           // row 48
    BODY(p1)           // row 49

    // ---- write this wave's partial slot (no LDS, no barrier) ----
    const int slot = s * 2 + w;
    float* pa_ = part_acc + (((size_t)b * NSLOT + slot) * NHEADS) * DD + j * 8;
    *reinterpret_cast<float4*>(pa_ + (2 * g) * DD)         = A0;
    *reinterpret_cast<float4*>(pa_ + (2 * g) * DD + 4)     = A1;
    *reinterpret_cast<float4*>(pa_ + (2 * g + 1) * DD)     = B0;
    *reinterpret_cast<float4*>(pa_ + (2 * g + 1) * DD + 4) = B1;
    if (j == 0) {
        float* pd = part_den + ((size_t)b * NSLOT + slot) * NHEADS;
        pd[2 * g]     = den0;
        pd[2 * g + 1] = den1;
    }
}

// ---------------- kernel 2: combine slots + Wv/Wfc projections --------------
__global__ __launch_bounds__(128) void attn_combine_kernel(
    const float* __restrict__ part_acc,  // [B][NSLOT][8][128]
    const float* __restrict__ part_den,  // [B][NSLOT][8]
    const float* __restrict__ Wv,        // [128][128]
    const float* __restrict__ Wfc,       // [128][128]
    float* __restrict__ out)             // [B][128]
{
    const int b = blockIdx.x;
    const int t = threadIdx.x;   // 128 threads

    __shared__ float s_dn[NHEADS];
    __shared__ float s_ca[NHEADS][132];
    __shared__ float s_o2[HH];

    if (t < NHEADS) {
        float dn = 0.f;
        #pragma unroll
        for (int sp = 0; sp < NSLOT; ++sp)
            dn += part_den[((size_t)b * NSLOT + sp) * NHEADS + t];
        s_dn[t] = dn;
    }
    __syncthreads();

    {
        const int d = t;
        #pragma unroll
        for (int h = 0; h < NHEADS; ++h) {
            float a = 0.f;
            #pragma unroll
            for (int sp = 0; sp < NSLOT; ++sp)
                a += part_acc[(((size_t)b * NSLOT + sp) * NHEADS + h) * DD + d];
            s_ca[h][d] = a / s_dn[h];
        }
    }
    __syncthreads();

    {
        const int h = t >> 4;
        const float* wvr = Wv + (size_t)t * DD;
        float a = 0.f;
        #pragma unroll 4
        for (int d = 0; d < DD; ++d) a = fmaf(s_ca[h][d], wvr[d], a);
        s_o2[t] = a;
    }
    __syncthreads();

    {
        const float* wfc = Wfc + (size_t)t * DD;
        float a = 0.f;
        #pragma unroll 4
        for (int k = 0; k < DD; ++k) a = fmaf(s_o2[k], wfc[k], a);
        out[(size_t)b * HH + t] = a;
    }
}

extern "C" void kernel_launch(void* const* d_in, const int* in_sizes, int n_in,
                              void* d_out, int out_size, void* d_ws, size_t ws_size,
                              hipStream_t stream) {
    const float* state_t = (const float*)d_in[0];
    const float* context = (const float*)d_in[1];
    const int*   mask    = (const int*)d_in[2];
    const float* Wq      = (const float*)d_in[3];
    const float* Wk      = (const float*)d_in[4];
    const float* Wv      = (const float*)d_in[5];
    const float* Wfc     = (const float*)d_in[6];
    float* out = (float*)d_out;

    float* qw       = (float*)d_ws;                                  // 2 MB
    float* part_acc = qw + (size_t)NB * NHEADS * DD;                 // 21 MB
    float* part_den = part_acc + (size_t)NB * NSLOT * NHEADS * DD;   // 0.3 MB

    qw_kernel<<<dim3(NB), dim3(256), 0, stream>>>(state_t, Wq, Wk, qw);
    attn_partial_kernel<<<dim3(NSPLIT, NB), dim3(128), 0, stream>>>(
        context, mask, qw, part_acc, part_den);
    attn_combine_kernel<<<dim3(NB), dim3(128), 0, stream>>>(
        part_acc, part_den, Wv, Wfc, out);
}